// Round 18
// baseline (193.028 us; speedup 1.0000x reference)
//
#include <hip/hip_runtime.h>
#include <hip/hip_bf16.h>
#include <math.h>

#define EPSC 1e-5f

typedef __attribute__((ext_vector_type(8))) short bf16x8;
typedef __attribute__((ext_vector_type(4))) float f32x4;
typedef __attribute__((ext_vector_type(8))) unsigned short u16x8;

constexpr int Bn = 16, Cn = 96, Hn = 112, Wn = 112, HWn = Hn * Wn; // 12544
constexpr int NT = 64, TPI = HWn / NT;                             // 196
// LDS row strides (ushorts), chosen so b128 reads are <=4-way bank conflicted
// (was 104/200: 52/100 dwords = 20/4 mod 32 -> 8-way classes; now 54/102 dwords).
constexpr int FST = 108;   // ffn / fc1 slab stride
constexpr int GST = 204;   // grapher tile stride

#define MFMA16(a, b, c) __builtin_amdgcn_mfma_f32_16x16x32_bf16((a), (b), (c), 0, 0, 0)

// HIP cast lowers to hardware v_cvt_pk_bf16_f32 — do NOT hand-roll (r16 lesson: -4%).
__device__ __forceinline__ ushort f2bf(float f) {
    __hip_bfloat16 h = __float2bfloat16(f);
    return __builtin_bit_cast(ushort, h);
}
__device__ __forceinline__ float bf2f(ushort u) {
    return __builtin_bit_cast(float, (unsigned)u << 16);
}
// sigmoid-form GELU: x * sigmoid(1.702*x)  (r15-validated)
__device__ __forceinline__ float gelu_f(float x) {
    float e = __expf(-1.702f * x);
    return __fdividef(x, 1.0f + e);
}

// ---------------- weight pack + BN folding (merged; params on block 540) ----------------
__global__ __launch_bounds__(256) void pack_kernel(
    const float* __restrict__ w1, const float* __restrict__ wg, const float* __restrict__ w2,
    const float* __restrict__ wf1, const float* __restrict__ wf2,
    const float* __restrict__ b1, const float* __restrict__ g1, const float* __restrict__ be1,
    const float* __restrict__ m1, const float* __restrict__ v1,
    const float* __restrict__ bg, const float* __restrict__ gg, const float* __restrict__ beg,
    const float* __restrict__ mg, const float* __restrict__ vg,
    const float* __restrict__ b2, const float* __restrict__ g2, const float* __restrict__ be2,
    const float* __restrict__ m2, const float* __restrict__ v2,
    ushort* __restrict__ dst, float* __restrict__ P)
{
    if (blockIdx.x == 540) {
        int t = threadIdx.x;
        if (t < 96) {
            float s = g1[t] * rsqrtf(v1[t] + EPSC);
            P[t]       = s;
            P[96 + t]  = (b1[t] - m1[t]) * s + be1[t];
            float s2 = g2[t] * rsqrtf(v2[t] + EPSC);
            P[576 + t] = s2;
            P[672 + t] = (b2[t] - m2[t]) * s2 + be2[t];
        }
        if (t < 192) {
            float s = gg[t] * rsqrtf(vg[t] + EPSC);
            P[192 + t] = s;
            P[384 + t] = (bg[t] - mg[t]) * s + beg[t];
        }
        return;
    }
    int idx = blockIdx.x * 256 + threadIdx.x;
    if (idx >= 138240) return;
    const float* src; int K, off;
    if      (idx <   9216) { src = w1;  K =  96; off = 0;      }
    else if (idx <  46080) { src = wg;  K = 192; off = 9216;   }
    else if (idx <  64512) { src = w2;  K = 192; off = 46080;  }
    else if (idx < 101376) { src = wf1; K =  96; off = 64512;  }
    else                   { src = wf2; K = 384; off = 101376; }
    int r = idx - off;
    int e = r & 7, lane = (r >> 3) & 63, tile = r >> 9;
    int KC = K / 32;
    int kc = tile % KC, mt = tile / KC;
    int row = mt * 16 + (lane & 15);
    int col = kc * 32 + (lane >> 4) * 8 + e;
    dst[idx] = f2bf(src[(size_t)row * K + col]);
}

// ---------------- parity mins ----------------
__global__ __launch_bounds__(256) void mins_kernel(
    const ushort* __restrict__ h, float* __restrict__ rmin2, float* __restrict__ cmin2)
{
    __shared__ __align__(16) ushort sl[112 * 96];
    int bid = blockIdx.x;            // Bn * 2 * 112
    int b = bid / 224, rem = bid % 224, mode = rem / 112, line = rem % 112;
    int t = threadIdx.x;
    if (mode == 0) {
        const ushort* base = h + ((size_t)b * HWn + line * Wn) * Cn;
        for (int v = t; v < 1344; v += 256)
            *(u16x8*)&sl[v * 8] = *(const u16x8*)&base[v * 8];
    } else {
        for (int v = t; v < 1344; v += 256) {
            int i = v / 12, g = v % 12;
            *(u16x8*)&sl[(i * 12 + g) * 8] =
                *(const u16x8*)&h[((size_t)b * HWn + i * Wn + line) * Cn + g * 8];
        }
    }
    __syncthreads();
    if (t < 192) {
        int c = t % 96, p = t / 96;
        float m = 1e30f;
        #pragma unroll 8
        for (int n = 0; n < 56; ++n) m = fminf(m, bf2f(sl[(p + 2 * n) * 96 + c]));
        float* dst = (mode == 0) ? rmin2 : cmin2;
        dst[(((size_t)b * 112 + line) * 2 + p) * 96 + c] = m;
    }
}

// ---------------- fc1: h = BN(W1 x) -> bf16 [b][hw][96] ----------------
__global__ __launch_bounds__(256) void fc1_kernel(
    const float* __restrict__ X, const ushort* __restrict__ w1p,
    const float* __restrict__ prm, ushort* __restrict__ hbuf)
{
    __shared__ __align__(16) ushort Hs[64 * FST];
    int bid = blockIdx.x, b = bid / TPI, hw0 = (bid % TPI) * NT;
    int t = threadIdx.x, lane = t & 63, wave = t >> 6;
    int wm = wave >> 1, wn = wave & 1, q = lane >> 4, sl = lane & 15;

    bf16x8 bfr[3][2];
    #pragma unroll
    for (int kc = 0; kc < 3; ++kc)
        #pragma unroll
        for (int nc = 0; nc < 2; ++nc) {
            int s = hw0 + wn * 32 + nc * 16 + sl;
            union { bf16x8 v; ushort u[8]; } f;
            #pragma unroll
            for (int e = 0; e < 8; ++e) {
                int c = kc * 32 + q * 8 + e;
                f.u[e] = f2bf(X[((size_t)b * Cn + c) * HWn + s]);
            }
            bfr[kc][nc] = f.v;
        }
    f32x4 acc[3][2] = {};
    #pragma unroll
    for (int kc = 0; kc < 3; ++kc)
        #pragma unroll
        for (int m = 0; m < 3; ++m) {
            bf16x8 af = *(const bf16x8*)&w1p[(((wm * 3 + m) * 3 + kc) * 64 + lane) * 8];
            acc[m][0] = MFMA16(af, bfr[kc][0], acc[m][0]);
            acc[m][1] = MFMA16(af, bfr[kc][1], acc[m][1]);
        }
    #pragma unroll
    for (int m = 0; m < 3; ++m) {
        int o0 = (wm * 3 + m) * 16 + q * 4;
        f32x4 a4 = *(const f32x4*)&prm[o0];
        f32x4 s4 = *(const f32x4*)&prm[96 + o0];
        #pragma unroll
        for (int nc = 0; nc < 2; ++nc) {
            int srow = wn * 32 + nc * 16 + sl;
            ushort4 pk;
            pk.x = f2bf(acc[m][nc][0] * a4[0] + s4[0]);
            pk.y = f2bf(acc[m][nc][1] * a4[1] + s4[1]);
            pk.z = f2bf(acc[m][nc][2] * a4[2] + s4[2]);
            pk.w = f2bf(acc[m][nc][3] * a4[3] + s4[3]);
            *(ushort4*)&Hs[srow * FST + o0] = pk;
        }
    }
    __syncthreads();
    for (int v = t; v < 768; v += 256) {
        int s = v / 12, g = v % 12;
        *(u16x8*)&hbuf[((size_t)b * HWn + hw0 + s) * Cn + g * 8] = *(const u16x8*)&Hs[s * FST + g * 8];
    }
}

// ---------------- grapher: cat -> fcg+BN+GELU -> fc2+BN+residual -> r ----------------
__global__ __launch_bounds__(256) void grapher_kernel(
    const ushort* __restrict__ hbuf, const float* __restrict__ Xres,
    const ushort* __restrict__ wgp, const ushort* __restrict__ w2p,
    const float* __restrict__ prm,
    const float* __restrict__ cmin2, const float* __restrict__ rmin2,
    ushort* __restrict__ rbuf)
{
    __shared__ __align__(16) ushort Xs[64 * GST];
    __shared__ __align__(16) ushort Gs[64 * GST];
    int bid = blockIdx.x, b = bid / TPI, hw0 = (bid % TPI) * NT;
    int t = threadIdx.x, lane = t & 63, wave = t >> 6;
    int wm = wave >> 1, wn = wave & 1, q = lane >> 4, sl = lane & 15;

    for (int v = t; v < 768; v += 256) {
        int s = v / 12, g = v % 12;
        u16x8 hv = *(const u16x8*)&hbuf[((size_t)b * HWn + hw0 + s) * Cn + g * 8];
        *(u16x8*)&Xs[s * GST + g * 8] = hv;
        int pos = hw0 + s, i = pos / Wn, j = pos - i * Wn;
        const float* cm = &cmin2[(((size_t)b * 112 + j) * 2 + (i & 1)) * 96 + g * 8];
        const float* rm = &rmin2[(((size_t)b * 112 + i) * 2 + (j & 1)) * 96 + g * 8];
        union { u16x8 v; ushort u[8]; } hh, xx;
        hh.v = hv;
        #pragma unroll
        for (int e = 0; e < 8; ++e) {
            float hf = bf2f(hh.u[e]);
            xx.u[e] = f2bf(fmaxf(hf - cm[e], hf - rm[e]));
        }
        *(u16x8*)&Xs[s * GST + 96 + g * 8] = xx.v;
    }
    __syncthreads();

    // fcg: M=192, K=192
    f32x4 acc[6][2] = {};
    #pragma unroll
    for (int kc = 0; kc < 6; ++kc) {
        bf16x8 b0 = *(const bf16x8*)&Xs[(wn * 32 + sl) * GST + kc * 32 + q * 8];
        bf16x8 b1 = *(const bf16x8*)&Xs[(wn * 32 + 16 + sl) * GST + kc * 32 + q * 8];
        #pragma unroll
        for (int m = 0; m < 6; ++m) {
            bf16x8 af = *(const bf16x8*)&wgp[(((wm * 6 + m) * 6 + kc) * 64 + lane) * 8];
            acc[m][0] = MFMA16(af, b0, acc[m][0]);
            acc[m][1] = MFMA16(af, b1, acc[m][1]);
        }
    }
    #pragma unroll
    for (int m = 0; m < 6; ++m) {
        int o0 = (wm * 6 + m) * 16 + q * 4;
        f32x4 a4 = *(const f32x4*)&prm[192 + o0];
        f32x4 s4 = *(const f32x4*)&prm[384 + o0];
        #pragma unroll
        for (int nc = 0; nc < 2; ++nc) {
            int srow = wn * 32 + nc * 16 + sl;
            ushort4 pk;
            pk.x = f2bf(gelu_f(acc[m][nc][0] * a4[0] + s4[0]));
            pk.y = f2bf(gelu_f(acc[m][nc][1] * a4[1] + s4[1]));
            pk.z = f2bf(gelu_f(acc[m][nc][2] * a4[2] + s4[2]));
            pk.w = f2bf(gelu_f(acc[m][nc][3] * a4[3] + s4[3]));
            *(ushort4*)&Gs[srow * GST + o0] = pk;
        }
    }
    __syncthreads();

    // fc2: M=96, K=192
    f32x4 acc2[3][2] = {};
    #pragma unroll
    for (int kc = 0; kc < 6; ++kc) {
        bf16x8 b0 = *(const bf16x8*)&Gs[(wn * 32 + sl) * GST + kc * 32 + q * 8];
        bf16x8 b1 = *(const bf16x8*)&Gs[(wn * 32 + 16 + sl) * GST + kc * 32 + q * 8];
        #pragma unroll
        for (int m = 0; m < 3; ++m) {
            bf16x8 af = *(const bf16x8*)&w2p[(((wm * 3 + m) * 6 + kc) * 64 + lane) * 8];
            acc2[m][0] = MFMA16(af, b0, acc2[m][0]);
            acc2[m][1] = MFMA16(af, b1, acc2[m][1]);
        }
    }
    #pragma unroll
    for (int m = 0; m < 3; ++m) {
        int o0 = (wm * 3 + m) * 16 + q * 4;
        f32x4 a4 = *(const f32x4*)&prm[576 + o0];
        f32x4 s4 = *(const f32x4*)&prm[672 + o0];
        #pragma unroll
        for (int nc = 0; nc < 2; ++nc) {
            int srow = wn * 32 + nc * 16 + sl, sgl = hw0 + srow;
            ushort4 pk;
            float r0 = acc2[m][nc][0] * a4[0] + s4[0] + Xres[((size_t)b * Cn + o0 + 0) * HWn + sgl];
            float r1 = acc2[m][nc][1] * a4[1] + s4[1] + Xres[((size_t)b * Cn + o0 + 1) * HWn + sgl];
            float r2 = acc2[m][nc][2] * a4[2] + s4[2] + Xres[((size_t)b * Cn + o0 + 2) * HWn + sgl];
            float r3 = acc2[m][nc][3] * a4[3] + s4[3] + Xres[((size_t)b * Cn + o0 + 3) * HWn + sgl];
            pk.x = f2bf(r0); pk.y = f2bf(r1); pk.z = f2bf(r2); pk.w = f2bf(r3);
            *(ushort4*)&Xs[srow * GST + o0] = pk;
        }
    }
    __syncthreads();
    for (int v = t; v < 768; v += 256) {
        int s = v / 12, g = v % 12;
        *(u16x8*)&rbuf[((size_t)b * HWn + hw0 + s) * Cn + g * 8] = *(const u16x8*)&Xs[s * GST + g * 8];
    }
}

// ---------------- FFN: chunked + w2f pre-barrier prefetch (r15 structure, padded slabs) ----------------
__global__ __launch_bounds__(256) void ffn_kernel(
    const ushort* __restrict__ rbuf,
    const ushort* __restrict__ wf1p, const float* __restrict__ bf1,
    const ushort* __restrict__ wf2p, const float* __restrict__ bf2,
    float* __restrict__ Out)
{
    __shared__ __align__(16) ushort S[2 * 64 * FST];  // 27.6 KB: slab0 | slab1(=Rs)
    ushort* slab0 = S;
    ushort* Rs    = S + 64 * FST;                     // staging + odd-chunk mid
    int bid = blockIdx.x, b = bid / TPI, hw0 = (bid % TPI) * NT;
    int t = threadIdx.x, lane = t & 63, wave = t >> 6;
    int wm = wave >> 1, wn = wave & 1, q = lane >> 4, sl = lane & 15;

    for (int v = t; v < 768; v += 256) {
        int s = v / 12, g = v % 12;
        *(u16x8*)&Rs[s * FST + g * 8] = *(const u16x8*)&rbuf[((size_t)b * HWn + hw0 + s) * Cn + g * 8];
    }
    __syncthreads();

    bf16x8 rb[3][2];
    #pragma unroll
    for (int kc = 0; kc < 3; ++kc) {
        rb[kc][0] = *(const bf16x8*)&Rs[(wn * 32 + sl) * FST + kc * 32 + q * 8];
        rb[kc][1] = *(const bf16x8*)&Rs[(wn * 32 + 16 + sl) * FST + kc * 32 + q * 8];
    }

    f32x4 acc2[3][2] = {};
    #pragma unroll 1
    for (int c = 0; c < 4; ++c) {
        // ffn1 slice: global mt = c*6 + wm*3 + m, K=96 (3 kc)
        f32x4 a1[3][2] = {};
        #pragma unroll
        for (int kc = 0; kc < 3; ++kc)
            #pragma unroll
            for (int m = 0; m < 3; ++m) {
                bf16x8 af = *(const bf16x8*)&wf1p[(((c * 6 + wm * 3 + m) * 3 + kc) * 64 + lane) * 8];
                a1[m][0] = MFMA16(af, rb[kc][0], a1[m][0]);
                a1[m][1] = MFMA16(af, rb[kc][1], a1[m][1]);
            }
        // ---- PREFETCH: this chunk's wf2 A-frags into registers (consumed post-bar) ----
        bf16x8 w2f[3][3];
        #pragma unroll
        for (int kc = 0; kc < 3; ++kc)
            #pragma unroll
            for (int m = 0; m < 3; ++m)
                w2f[kc][m] = *(const bf16x8*)&wf2p[(((wm * 3 + m) * 12 + c * 3 + kc) * 64 + lane) * 8];
        // epilogue: gelu -> chunk slab (loads above drain under this VALU work)
        ushort* mc = (c & 1) ? Rs : slab0;
        #pragma unroll
        for (int m = 0; m < 3; ++m) {
            int ol = (wm * 3 + m) * 16 + q * 4;          // 0..95 within chunk
            f32x4 b4 = *(const f32x4*)&bf1[c * 96 + ol];
            #pragma unroll
            for (int nc = 0; nc < 2; ++nc) {
                int srow = wn * 32 + nc * 16 + sl;
                ushort4 pk;
                pk.x = f2bf(gelu_f(a1[m][nc][0] + b4[0]));
                pk.y = f2bf(gelu_f(a1[m][nc][1] + b4[1]));
                pk.z = f2bf(gelu_f(a1[m][nc][2] + b4[2]));
                pk.w = f2bf(gelu_f(a1[m][nc][3] + b4[3]));
                *(ushort4*)&mc[srow * FST + ol] = pk;
            }
        }
        __syncthreads();
        // ffn2 partial accumulation: weights already in w2f registers
        #pragma unroll
        for (int kc = 0; kc < 3; ++kc) {
            bf16x8 m0 = *(const bf16x8*)&mc[(wn * 32 + sl) * FST + kc * 32 + q * 8];
            bf16x8 m1 = *(const bf16x8*)&mc[(wn * 32 + 16 + sl) * FST + kc * 32 + q * 8];
            acc2[0][0] = MFMA16(w2f[kc][0], m0, acc2[0][0]);
            acc2[0][1] = MFMA16(w2f[kc][0], m1, acc2[0][1]);
            acc2[1][0] = MFMA16(w2f[kc][1], m0, acc2[1][0]);
            acc2[1][1] = MFMA16(w2f[kc][1], m1, acc2[1][1]);
            acc2[2][0] = MFMA16(w2f[kc][2], m0, acc2[2][0]);
            acc2[2][1] = MFMA16(w2f[kc][2], m1, acc2[2][1]);
        }
        // no trailing barrier: next chunk writes the OTHER slab; its barrier
        // orders those writes against this chunk's reads (double-buffer, r5-proven).
    }
    #pragma unroll
    for (int m = 0; m < 3; ++m) {
        int o0 = (wm * 3 + m) * 16 + q * 4;
        f32x4 b4 = *(const f32x4*)&bf2[o0];
        #pragma unroll
        for (int nc = 0; nc < 2; ++nc) {
            int sgl = hw0 + wn * 32 + nc * 16 + sl;
            Out[((size_t)b * Cn + o0 + 0) * HWn + sgl] = acc2[m][nc][0] + b4[0];
            Out[((size_t)b * Cn + o0 + 1) * HWn + sgl] = acc2[m][nc][1] + b4[1];
            Out[((size_t)b * Cn + o0 + 2) * HWn + sgl] = acc2[m][nc][2] + b4[2];
            Out[((size_t)b * Cn + o0 + 3) * HWn + sgl] = acc2[m][nc][3] + b4[3];
        }
    }
}

extern "C" void kernel_launch(void* const* d_in, const int* in_sizes, int n_in,
                              void* d_out, int out_size, void* d_ws, size_t ws_size,
                              hipStream_t stream) {
    (void)in_sizes; (void)n_in; (void)out_size; (void)ws_size;
    const float* x   = (const float*)d_in[0];
    const float* w1  = (const float*)d_in[1];
    const float* b1  = (const float*)d_in[2];
    const float* g1  = (const float*)d_in[3];
    const float* be1 = (const float*)d_in[4];
    const float* m1  = (const float*)d_in[5];
    const float* v1  = (const float*)d_in[6];
    const float* wg  = (const float*)d_in[7];
    const float* bg  = (const float*)d_in[8];
    const float* gg  = (const float*)d_in[9];
    const float* beg = (const float*)d_in[10];
    const float* mg  = (const float*)d_in[11];
    const float* vg  = (const float*)d_in[12];
    const float* w2  = (const float*)d_in[13];
    const float* b2  = (const float*)d_in[14];
    const float* g2  = (const float*)d_in[15];
    const float* be2 = (const float*)d_in[16];
    const float* m2  = (const float*)d_in[17];
    const float* v2  = (const float*)d_in[18];
    const float* wf1 = (const float*)d_in[19];
    const float* bf1 = (const float*)d_in[20];
    const float* wf2 = (const float*)d_in[21];
    const float* bf2 = (const float*)d_in[22];
    float* out = (float*)d_out;

    char* base = (char*)d_ws;
    const size_t H_BYTES   = (size_t)Bn * HWn * Cn * 2;
    const size_t MIN_BYTES = (size_t)Bn * 112 * 2 * 96 * 4;
    ushort* hbuf  = (ushort*)base;                         // h, overwritten by r
    float*  rmin2 = (float*)(base + H_BYTES);
    float*  cmin2 = (float*)(base + H_BYTES + MIN_BYTES);
    float*  prm   = (float*)(base + H_BYTES + 2 * MIN_BYTES);
    ushort* wpack = (ushort*)(base + H_BYTES + 2 * MIN_BYTES + 3072);
    ushort* w1p  = wpack;
    ushort* wgp  = wpack + 9216;
    ushort* w2p  = wpack + 46080;
    ushort* wf1p = wpack + 64512;
    ushort* wf2p = wpack + 101376;

    pack_kernel<<<dim3(541), dim3(256), 0, stream>>>(
        w1, wg, w2, wf1, wf2,
        b1, g1, be1, m1, v1, bg, gg, beg, mg, vg, b2, g2, be2, m2, v2,
        wpack, prm);

    dim3 blk(256);
    fc1_kernel<<<dim3(Bn * TPI), blk, 0, stream>>>(x, w1p, prm, hbuf);
    mins_kernel<<<dim3(Bn * 2 * 112), blk, 0, stream>>>(hbuf, rmin2, cmin2);
    grapher_kernel<<<dim3(Bn * TPI), blk, 0, stream>>>(hbuf, x, wgp, w2p, prm, cmin2, rmin2, hbuf);
    ffn_kernel<<<dim3(Bn * TPI), blk, 0, stream>>>(hbuf, wf1p, bf1, wf2p, bf2, out);
}

// Round 19
// 185.293 us; speedup vs baseline: 1.0417x; 1.0417x over previous
//
#include <hip/hip_runtime.h>
#include <hip/hip_bf16.h>
#include <math.h>

#define EPSC 1e-5f

typedef __attribute__((ext_vector_type(8))) short bf16x8;
typedef __attribute__((ext_vector_type(4))) float f32x4;
typedef __attribute__((ext_vector_type(8))) unsigned short u16x8;

constexpr int Bn = 16, Cn = 96, Hn = 112, Wn = 112, HWn = Hn * Wn; // 12544
constexpr int NT = 64, TPI = HWn / NT;                             // 196

#define MFMA16(a, b, c) __builtin_amdgcn_mfma_f32_16x16x32_bf16((a), (b), (c), 0, 0, 0)

// HIP cast lowers to hardware v_cvt_pk_bf16_f32 — do NOT hand-roll (r16 lesson: -4%).
__device__ __forceinline__ ushort f2bf(float f) {
    __hip_bfloat16 h = __float2bfloat16(f);
    return __builtin_bit_cast(ushort, h);
}
__device__ __forceinline__ float bf2f(ushort u) {
    return __builtin_bit_cast(float, (unsigned)u << 16);
}
// sigmoid-form GELU: x * sigmoid(1.702*x)  (r15-validated)
__device__ __forceinline__ float gelu_f(float x) {
    float e = __expf(-1.702f * x);
    return __fdividef(x, 1.0f + e);
}

// ---------------- weight pack + BN folding (merged; params on block 540) ----------------
// pack: element (mt,kc,lane,e) = W[mt*16 + lane%16][kc*32 + (lane>>4)*8 + e]
// prm: A1[0:96] B1[96:192] Ag[192:384] Bg[384:576] A2[576:672] B2[672:768]
__global__ __launch_bounds__(256) void pack_kernel(
    const float* __restrict__ w1, const float* __restrict__ wg, const float* __restrict__ w2,
    const float* __restrict__ wf1, const float* __restrict__ wf2,
    const float* __restrict__ b1, const float* __restrict__ g1, const float* __restrict__ be1,
    const float* __restrict__ m1, const float* __restrict__ v1,
    const float* __restrict__ bg, const float* __restrict__ gg, const float* __restrict__ beg,
    const float* __restrict__ mg, const float* __restrict__ vg,
    const float* __restrict__ b2, const float* __restrict__ g2, const float* __restrict__ be2,
    const float* __restrict__ m2, const float* __restrict__ v2,
    ushort* __restrict__ dst, float* __restrict__ P)
{
    if (blockIdx.x == 540) {
        int t = threadIdx.x;
        if (t < 96) {
            float s = g1[t] * rsqrtf(v1[t] + EPSC);
            P[t]       = s;
            P[96 + t]  = (b1[t] - m1[t]) * s + be1[t];
            float s2 = g2[t] * rsqrtf(v2[t] + EPSC);
            P[576 + t] = s2;
            P[672 + t] = (b2[t] - m2[t]) * s2 + be2[t];
        }
        if (t < 192) {
            float s = gg[t] * rsqrtf(vg[t] + EPSC);
            P[192 + t] = s;
            P[384 + t] = (bg[t] - mg[t]) * s + beg[t];
        }
        return;
    }
    int idx = blockIdx.x * 256 + threadIdx.x;
    if (idx >= 138240) return;
    const float* src; int K, off;
    if      (idx <   9216) { src = w1;  K =  96; off = 0;      }
    else if (idx <  46080) { src = wg;  K = 192; off = 9216;   }
    else if (idx <  64512) { src = w2;  K = 192; off = 46080;  }
    else if (idx < 101376) { src = wf1; K =  96; off = 64512;  }
    else                   { src = wf2; K = 384; off = 101376; }
    int r = idx - off;
    int e = r & 7, lane = (r >> 3) & 63, tile = r >> 9;
    int KC = K / 32;
    int kc = tile % KC, mt = tile / KC;
    int row = mt * 16 + (lane & 15);
    int col = kc * 32 + (lane >> 4) * 8 + e;
    dst[idx] = f2bf(src[(size_t)row * K + col]);
}

// ---------------- parity mins ----------------
__global__ __launch_bounds__(256) void mins_kernel(
    const ushort* __restrict__ h, float* __restrict__ rmin2, float* __restrict__ cmin2)
{
    __shared__ __align__(16) ushort sl[112 * 96];
    int bid = blockIdx.x;            // Bn * 2 * 112
    int b = bid / 224, rem = bid % 224, mode = rem / 112, line = rem % 112;
    int t = threadIdx.x;
    if (mode == 0) {
        const ushort* base = h + ((size_t)b * HWn + line * Wn) * Cn;
        for (int v = t; v < 1344; v += 256)
            *(u16x8*)&sl[v * 8] = *(const u16x8*)&base[v * 8];
    } else {
        for (int v = t; v < 1344; v += 256) {
            int i = v / 12, g = v % 12;
            *(u16x8*)&sl[(i * 12 + g) * 8] =
                *(const u16x8*)&h[((size_t)b * HWn + i * Wn + line) * Cn + g * 8];
        }
    }
    __syncthreads();
    if (t < 192) {
        int c = t % 96, p = t / 96;
        float m = 1e30f;
        #pragma unroll 8
        for (int n = 0; n < 56; ++n) m = fminf(m, bf2f(sl[(p + 2 * n) * 96 + c]));
        float* dst = (mode == 0) ? rmin2 : cmin2;
        dst[(((size_t)b * 112 + line) * 2 + p) * 96 + c] = m;
    }
}

// ---------------- fc1: h = BN(W1 x) -> bf16 [b][hw][96] ----------------
__global__ __launch_bounds__(256) void fc1_kernel(
    const float* __restrict__ X, const ushort* __restrict__ w1p,
    const float* __restrict__ prm, ushort* __restrict__ hbuf)
{
    __shared__ __align__(16) ushort Hs[64 * 104];
    int bid = blockIdx.x, b = bid / TPI, hw0 = (bid % TPI) * NT;
    int t = threadIdx.x, lane = t & 63, wave = t >> 6;
    int wm = wave >> 1, wn = wave & 1, q = lane >> 4, sl = lane & 15;

    bf16x8 bfr[3][2];
    #pragma unroll
    for (int kc = 0; kc < 3; ++kc)
        #pragma unroll
        for (int nc = 0; nc < 2; ++nc) {
            int s = hw0 + wn * 32 + nc * 16 + sl;
            union { bf16x8 v; ushort u[8]; } f;
            #pragma unroll
            for (int e = 0; e < 8; ++e) {
                int c = kc * 32 + q * 8 + e;
                f.u[e] = f2bf(X[((size_t)b * Cn + c) * HWn + s]);
            }
            bfr[kc][nc] = f.v;
        }
    f32x4 acc[3][2] = {};
    #pragma unroll
    for (int kc = 0; kc < 3; ++kc)
        #pragma unroll
        for (int m = 0; m < 3; ++m) {
            bf16x8 af = *(const bf16x8*)&w1p[(((wm * 3 + m) * 3 + kc) * 64 + lane) * 8];
            acc[m][0] = MFMA16(af, bfr[kc][0], acc[m][0]);
            acc[m][1] = MFMA16(af, bfr[kc][1], acc[m][1]);
        }
    #pragma unroll
    for (int m = 0; m < 3; ++m) {
        int o0 = (wm * 3 + m) * 16 + q * 4;
        f32x4 a4 = *(const f32x4*)&prm[o0];
        f32x4 s4 = *(const f32x4*)&prm[96 + o0];
        #pragma unroll
        for (int nc = 0; nc < 2; ++nc) {
            int srow = wn * 32 + nc * 16 + sl;
            ushort4 pk;
            pk.x = f2bf(acc[m][nc][0] * a4[0] + s4[0]);
            pk.y = f2bf(acc[m][nc][1] * a4[1] + s4[1]);
            pk.z = f2bf(acc[m][nc][2] * a4[2] + s4[2]);
            pk.w = f2bf(acc[m][nc][3] * a4[3] + s4[3]);
            *(ushort4*)&Hs[srow * 104 + o0] = pk;
        }
    }
    __syncthreads();
    for (int v = t; v < 768; v += 256) {
        int s = v / 12, g = v % 12;
        *(u16x8*)&hbuf[((size_t)b * HWn + hw0 + s) * Cn + g * 8] = *(const u16x8*)&Hs[s * 104 + g * 8];
    }
}

// ---------------- grapher (r15-exact): cat -> fcg+BN+GELU -> fc2+BN+residual -> r ----------------
__global__ __launch_bounds__(256) void grapher_kernel(
    const ushort* __restrict__ hbuf, const float* __restrict__ Xres,
    const ushort* __restrict__ wgp, const ushort* __restrict__ w2p,
    const float* __restrict__ prm,
    const float* __restrict__ cmin2, const float* __restrict__ rmin2,
    ushort* __restrict__ rbuf)
{
    __shared__ __align__(16) ushort Xs[64 * 200];
    __shared__ __align__(16) ushort Gs[64 * 200];
    int bid = blockIdx.x, b = bid / TPI, hw0 = (bid % TPI) * NT;
    int t = threadIdx.x, lane = t & 63, wave = t >> 6;
    int wm = wave >> 1, wn = wave & 1, q = lane >> 4, sl = lane & 15;

    for (int v = t; v < 768; v += 256) {
        int s = v / 12, g = v % 12;
        u16x8 hv = *(const u16x8*)&hbuf[((size_t)b * HWn + hw0 + s) * Cn + g * 8];
        *(u16x8*)&Xs[s * 200 + g * 8] = hv;
        int pos = hw0 + s, i = pos / Wn, j = pos - i * Wn;
        const float* cm = &cmin2[(((size_t)b * 112 + j) * 2 + (i & 1)) * 96 + g * 8];
        const float* rm = &rmin2[(((size_t)b * 112 + i) * 2 + (j & 1)) * 96 + g * 8];
        union { u16x8 v; ushort u[8]; } hh, xx;
        hh.v = hv;
        #pragma unroll
        for (int e = 0; e < 8; ++e) {
            float hf = bf2f(hh.u[e]);
            xx.u[e] = f2bf(fmaxf(hf - cm[e], hf - rm[e]));
        }
        *(u16x8*)&Xs[s * 200 + 96 + g * 8] = xx.v;
    }
    __syncthreads();

    // fcg: M=192, K=192
    f32x4 acc[6][2] = {};
    #pragma unroll
    for (int kc = 0; kc < 6; ++kc) {
        bf16x8 b0 = *(const bf16x8*)&Xs[(wn * 32 + sl) * 200 + kc * 32 + q * 8];
        bf16x8 b1 = *(const bf16x8*)&Xs[(wn * 32 + 16 + sl) * 200 + kc * 32 + q * 8];
        #pragma unroll
        for (int m = 0; m < 6; ++m) {
            bf16x8 af = *(const bf16x8*)&wgp[(((wm * 6 + m) * 6 + kc) * 64 + lane) * 8];
            acc[m][0] = MFMA16(af, b0, acc[m][0]);
            acc[m][1] = MFMA16(af, b1, acc[m][1]);
        }
    }
    #pragma unroll
    for (int m = 0; m < 6; ++m) {
        int o0 = (wm * 6 + m) * 16 + q * 4;
        f32x4 a4 = *(const f32x4*)&prm[192 + o0];
        f32x4 s4 = *(const f32x4*)&prm[384 + o0];
        #pragma unroll
        for (int nc = 0; nc < 2; ++nc) {
            int srow = wn * 32 + nc * 16 + sl;
            ushort4 pk;
            pk.x = f2bf(gelu_f(acc[m][nc][0] * a4[0] + s4[0]));
            pk.y = f2bf(gelu_f(acc[m][nc][1] * a4[1] + s4[1]));
            pk.z = f2bf(gelu_f(acc[m][nc][2] * a4[2] + s4[2]));
            pk.w = f2bf(gelu_f(acc[m][nc][3] * a4[3] + s4[3]));
            *(ushort4*)&Gs[srow * 200 + o0] = pk;
        }
    }
    __syncthreads();

    // fc2: M=96, K=192
    f32x4 acc2[3][2] = {};
    #pragma unroll
    for (int kc = 0; kc < 6; ++kc) {
        bf16x8 b0 = *(const bf16x8*)&Gs[(wn * 32 + sl) * 200 + kc * 32 + q * 8];
        bf16x8 b1 = *(const bf16x8*)&Gs[(wn * 32 + 16 + sl) * 200 + kc * 32 + q * 8];
        #pragma unroll
        for (int m = 0; m < 3; ++m) {
            bf16x8 af = *(const bf16x8*)&w2p[(((wm * 3 + m) * 6 + kc) * 64 + lane) * 8];
            acc2[m][0] = MFMA16(af, b0, acc2[m][0]);
            acc2[m][1] = MFMA16(af, b1, acc2[m][1]);
        }
    }
    #pragma unroll
    for (int m = 0; m < 3; ++m) {
        int o0 = (wm * 3 + m) * 16 + q * 4;
        f32x4 a4 = *(const f32x4*)&prm[576 + o0];
        f32x4 s4 = *(const f32x4*)&prm[672 + o0];
        #pragma unroll
        for (int nc = 0; nc < 2; ++nc) {
            int srow = wn * 32 + nc * 16 + sl, sgl = hw0 + srow;
            ushort4 pk;
            float r0 = acc2[m][nc][0] * a4[0] + s4[0] + Xres[((size_t)b * Cn + o0 + 0) * HWn + sgl];
            float r1 = acc2[m][nc][1] * a4[1] + s4[1] + Xres[((size_t)b * Cn + o0 + 1) * HWn + sgl];
            float r2 = acc2[m][nc][2] * a4[2] + s4[2] + Xres[((size_t)b * Cn + o0 + 2) * HWn + sgl];
            float r3 = acc2[m][nc][3] * a4[3] + s4[3] + Xres[((size_t)b * Cn + o0 + 3) * HWn + sgl];
            pk.x = f2bf(r0); pk.y = f2bf(r1); pk.z = f2bf(r2); pk.w = f2bf(r3);
            *(ushort4*)&Xs[srow * 200 + o0] = pk;
        }
    }
    __syncthreads();
    for (int v = t; v < 768; v += 256) {
        int s = v / 12, g = v % 12;
        *(u16x8*)&rbuf[((size_t)b * HWn + hw0 + s) * Cn + g * 8] = *(const u16x8*)&Xs[s * 200 + g * 8];
    }
}

// ---------------- FFN (r15-exact): chunked + w2f pre-barrier prefetch ----------------
__global__ __launch_bounds__(256) void ffn_kernel(
    const ushort* __restrict__ rbuf,
    const ushort* __restrict__ wf1p, const float* __restrict__ bf1,
    const ushort* __restrict__ wf2p, const float* __restrict__ bf2,
    float* __restrict__ Out)
{
    __shared__ __align__(16) ushort S[2 * 6656];    // 26.6 KB: slab0 | slab1(=Rs)
    ushort* slab0 = S;
    ushort* Rs    = S + 6656;                       // staging + odd-chunk mid
    int bid = blockIdx.x, b = bid / TPI, hw0 = (bid % TPI) * NT;
    int t = threadIdx.x, lane = t & 63, wave = t >> 6;
    int wm = wave >> 1, wn = wave & 1, q = lane >> 4, sl = lane & 15;

    for (int v = t; v < 768; v += 256) {
        int s = v / 12, g = v % 12;
        *(u16x8*)&Rs[s * 104 + g * 8] = *(const u16x8*)&rbuf[((size_t)b * HWn + hw0 + s) * Cn + g * 8];
    }
    __syncthreads();

    bf16x8 rb[3][2];
    #pragma unroll
    for (int kc = 0; kc < 3; ++kc) {
        rb[kc][0] = *(const bf16x8*)&Rs[(wn * 32 + sl) * 104 + kc * 32 + q * 8];
        rb[kc][1] = *(const bf16x8*)&Rs[(wn * 32 + 16 + sl) * 104 + kc * 32 + q * 8];
    }

    f32x4 acc2[3][2] = {};
    #pragma unroll 1
    for (int c = 0; c < 4; ++c) {
        // ffn1 slice: global mt = c*6 + wm*3 + m, K=96 (3 kc)
        f32x4 a1[3][2] = {};
        #pragma unroll
        for (int kc = 0; kc < 3; ++kc)
            #pragma unroll
            for (int m = 0; m < 3; ++m) {
                bf16x8 af = *(const bf16x8*)&wf1p[(((c * 6 + wm * 3 + m) * 3 + kc) * 64 + lane) * 8];
                a1[m][0] = MFMA16(af, rb[kc][0], a1[m][0]);
                a1[m][1] = MFMA16(af, rb[kc][1], a1[m][1]);
            }
        // ---- PREFETCH: this chunk's wf2 A-frags into registers (consumed post-bar) ----
        bf16x8 w2f[3][3];
        #pragma unroll
        for (int kc = 0; kc < 3; ++kc)
            #pragma unroll
            for (int m = 0; m < 3; ++m)
                w2f[kc][m] = *(const bf16x8*)&wf2p[(((wm * 3 + m) * 12 + c * 3 + kc) * 64 + lane) * 8];
        // epilogue: gelu -> chunk slab (loads above drain under this VALU work)
        ushort* mc = (c & 1) ? Rs : slab0;
        #pragma unroll
        for (int m = 0; m < 3; ++m) {
            int ol = (wm * 3 + m) * 16 + q * 4;          // 0..95 within chunk
            f32x4 b4 = *(const f32x4*)&bf1[c * 96 + ol];
            #pragma unroll
            for (int nc = 0; nc < 2; ++nc) {
                int srow = wn * 32 + nc * 16 + sl;
                ushort4 pk;
                pk.x = f2bf(gelu_f(a1[m][nc][0] + b4[0]));
                pk.y = f2bf(gelu_f(a1[m][nc][1] + b4[1]));
                pk.z = f2bf(gelu_f(a1[m][nc][2] + b4[2]));
                pk.w = f2bf(gelu_f(a1[m][nc][3] + b4[3]));
                *(ushort4*)&mc[srow * 104 + ol] = pk;
            }
        }
        __syncthreads();
        // ffn2 partial accumulation: weights already in w2f registers
        #pragma unroll
        for (int kc = 0; kc < 3; ++kc) {
            bf16x8 m0 = *(const bf16x8*)&mc[(wn * 32 + sl) * 104 + kc * 32 + q * 8];
            bf16x8 m1 = *(const bf16x8*)&mc[(wn * 32 + 16 + sl) * 104 + kc * 32 + q * 8];
            acc2[0][0] = MFMA16(w2f[kc][0], m0, acc2[0][0]);
            acc2[0][1] = MFMA16(w2f[kc][0], m1, acc2[0][1]);
            acc2[1][0] = MFMA16(w2f[kc][1], m0, acc2[1][0]);
            acc2[1][1] = MFMA16(w2f[kc][1], m1, acc2[1][1]);
            acc2[2][0] = MFMA16(w2f[kc][2], m0, acc2[2][0]);
            acc2[2][1] = MFMA16(w2f[kc][2], m1, acc2[2][1]);
        }
        // no trailing barrier: next chunk writes the OTHER slab; its barrier
        // orders those writes against this chunk's reads (double-buffer, r5-proven).
    }
    #pragma unroll
    for (int m = 0; m < 3; ++m) {
        int o0 = (wm * 3 + m) * 16 + q * 4;
        f32x4 b4 = *(const f32x4*)&bf2[o0];
        #pragma unroll
        for (int nc = 0; nc < 2; ++nc) {
            int sgl = hw0 + wn * 32 + nc * 16 + sl;
            Out[((size_t)b * Cn + o0 + 0) * HWn + sgl] = acc2[m][nc][0] + b4[0];
            Out[((size_t)b * Cn + o0 + 1) * HWn + sgl] = acc2[m][nc][1] + b4[1];
            Out[((size_t)b * Cn + o0 + 2) * HWn + sgl] = acc2[m][nc][2] + b4[2];
            Out[((size_t)b * Cn + o0 + 3) * HWn + sgl] = acc2[m][nc][3] + b4[3];
        }
    }
}

extern "C" void kernel_launch(void* const* d_in, const int* in_sizes, int n_in,
                              void* d_out, int out_size, void* d_ws, size_t ws_size,
                              hipStream_t stream) {
    (void)in_sizes; (void)n_in; (void)out_size; (void)ws_size;
    const float* x   = (const float*)d_in[0];
    const float* w1  = (const float*)d_in[1];
    const float* b1  = (const float*)d_in[2];
    const float* g1  = (const float*)d_in[3];
    const float* be1 = (const float*)d_in[4];
    const float* m1  = (const float*)d_in[5];
    const float* v1  = (const float*)d_in[6];
    const float* wg  = (const float*)d_in[7];
    const float* bg  = (const float*)d_in[8];
    const float* gg  = (const float*)d_in[9];
    const float* beg = (const float*)d_in[10];
    const float* mg  = (const float*)d_in[11];
    const float* vg  = (const float*)d_in[12];
    const float* w2  = (const float*)d_in[13];
    const float* b2  = (const float*)d_in[14];
    const float* g2  = (const float*)d_in[15];
    const float* be2 = (const float*)d_in[16];
    const float* m2  = (const float*)d_in[17];
    const float* v2  = (const float*)d_in[18];
    const float* wf1 = (const float*)d_in[19];
    const float* bf1 = (const float*)d_in[20];
    const float* wf2 = (const float*)d_in[21];
    const float* bf2 = (const float*)d_in[22];
    float* out = (float*)d_out;

    char* base = (char*)d_ws;
    const size_t H_BYTES   = (size_t)Bn * HWn * Cn * 2;
    const size_t MIN_BYTES = (size_t)Bn * 112 * 2 * 96 * 4;
    ushort* hbuf  = (ushort*)base;                         // h, overwritten by r
    float*  rmin2 = (float*)(base + H_BYTES);
    float*  cmin2 = (float*)(base + H_BYTES + MIN_BYTES);
    float*  prm   = (float*)(base + H_BYTES + 2 * MIN_BYTES);
    ushort* wpack = (ushort*)(base + H_BYTES + 2 * MIN_BYTES + 3072);
    ushort* w1p  = wpack;
    ushort* wgp  = wpack + 9216;
    ushort* w2p  = wpack + 46080;
    ushort* wf1p = wpack + 64512;
    ushort* wf2p = wpack + 101376;

    pack_kernel<<<dim3(541), dim3(256), 0, stream>>>(
        w1, wg, w2, wf1, wf2,
        b1, g1, be1, m1, v1, bg, gg, beg, mg, vg, b2, g2, be2, m2, v2,
        wpack, prm);

    dim3 blk(256);
    fc1_kernel<<<dim3(Bn * TPI), blk, 0, stream>>>(x, w1p, prm, hbuf);
    mins_kernel<<<dim3(Bn * 2 * 112), blk, 0, stream>>>(hbuf, rmin2, cmin2);
    grapher_kernel<<<dim3(Bn * TPI), blk, 0, stream>>>(hbuf, x, wgp, w2p, prm, cmin2, rmin2, hbuf);
    ffn_kernel<<<dim3(Bn * TPI), blk, 0, stream>>>(hbuf, wf1p, bf1, wf2p, bf2, out);
}